// Round 10
// baseline (427.877 us; speedup 1.0000x reference)
//
#include <hip/hip_runtime.h>

#define SLOPE 0.01f

typedef __attribute__((ext_vector_type(8))) short short8;
typedef __attribute__((ext_vector_type(4))) float f32x4;
typedef unsigned short u16;
typedef unsigned int u32;

__device__ __forceinline__ float lrelu(float v) { return v >= 0.0f ? v : SLOPE * v; }

__device__ __forceinline__ u16 f2bf(float f) {
  u32 u = __float_as_uint(f);
  return (u16)((u + 0x7FFF + ((u >> 16) & 1)) >> 16);
}
__device__ __forceinline__ float bf2f(u16 h) {
  return __uint_as_float(((u32)h) << 16);
}
__device__ __forceinline__ float bflo(u32 u) { return __uint_as_float(u << 16); }
__device__ __forceinline__ float bfhi(u32 u) { return __uint_as_float(u & 0xffff0000u); }
__device__ __forceinline__ u32 packbf(float a, float b) {
  return ((u32)f2bf(b) << 16) | (u32)f2bf(a);
}
__device__ __forceinline__ void acc8(float* acc, uint4 a) {
  acc[0] += bflo(a.x); acc[1] += bfhi(a.x);
  acc[2] += bflo(a.y); acc[3] += bfhi(a.y);
  acc[4] += bflo(a.z); acc[5] += bfhi(a.z);
  acc[6] += bflo(a.w); acc[7] += bfhi(a.w);
}

// ---------------- CSR: bucket totals (512 cols per bucket) ----------------
__global__ __launch_bounds__(256) void bucket_cnt(const int* __restrict__ cols,
                                                  int* __restrict__ btot, int E, int NB) {
  __shared__ int h[256];
  const int t = threadIdx.x;
  const int e0 = blockIdx.x * 4096;
  const int end = min(e0 + 4096, E);
  h[t] = 0;
  __syncthreads();
  for (int i = e0 + t; i < end; i += 256) atomicAdd(&h[cols[i] >> 9], 1);
  __syncthreads();
  if (t < NB && h[t]) atomicAdd(&btot[t], h[t]);
}

__global__ __launch_bounds__(256) void scan_buckets(const int* __restrict__ btot,
                                                    int* __restrict__ bbase, int NB) {
  __shared__ int s[256];
  const int t = threadIdx.x;
  int v = (t < NB) ? btot[t] : 0;
  s[t] = v;
  __syncthreads();
  for (int d = 1; d < 256; d <<= 1) {
    int u = (t >= d) ? s[t - d] : 0;
    __syncthreads();
    s[t] += u;
    __syncthreads();
  }
  bbase[t] = s[t] - v;
}

// ---------------- CSR fill pass A: LDS bucket-binning ----------------
__global__ __launch_bounds__(256) void bin_pass(const int* __restrict__ rows,
                                                const int* __restrict__ cols,
                                                const int* __restrict__ bbase,
                                                int* __restrict__ gcur,
                                                int2* __restrict__ tmp,
                                                int E, int NB) {
  __shared__ int hist[256];
  __shared__ int scanbuf[256];
  __shared__ int lstart[256];
  __shared__ int lcur[256];
  __shared__ int gbase[256];
  __shared__ int2 stage[4096];
  const int t = threadIdx.x;
  const int e0 = blockIdx.x * 4096;
  const int cnt = min(4096, E - e0);

  hist[t] = 0;
  __syncthreads();

  int ec[16], er[16];
  int m = 0;
  for (int i = t; i < cnt; i += 256) {
    int c = cols[e0 + i], r = rows[e0 + i];
    ec[m] = c; er[m] = r; ++m;
    atomicAdd(&hist[c >> 9], 1);
  }
  __syncthreads();

  int v = hist[t];
  scanbuf[t] = v;
  __syncthreads();
  for (int d = 1; d < 256; d <<= 1) {
    int u = (t >= d) ? scanbuf[t - d] : 0;
    __syncthreads();
    scanbuf[t] += u;
    __syncthreads();
  }
  lstart[t] = scanbuf[t] - v;
  lcur[t] = 0;
  __syncthreads();

  for (int k = 0; k < m; ++k) {
    int b = ec[k] >> 9;
    int p = lstart[b] + atomicAdd(&lcur[b], 1);
    stage[p] = make_int2(ec[k], er[k]);
  }
  __syncthreads();

  if (t < NB && hist[t] > 0) {
    gbase[t] = bbase[t] + atomicAdd(&gcur[t], hist[t]);
  }
  __syncthreads();

  for (int i = t; i < cnt; i += 256) {
    int2 pr = stage[i];
    int b = pr.x >> 9;
    tmp[gbase[b] + (i - lstart[b])] = pr;
  }
}

// ---------------- CSR pass B: per-bucket hist + scan + scatter + flush ----------------
__global__ __launch_bounds__(256) void bucket_csr(const int2* __restrict__ tmp,
                                                  const int* __restrict__ bbase,
                                                  int* __restrict__ off,
                                                  float* __restrict__ dis,
                                                  int* __restrict__ csr, int n, int NB) {
  const int b = blockIdx.x;
  const int c0 = b << 9;
  const int ncols = min(512, n - c0);
  __shared__ int hist[512];
  __shared__ int scanbuf[256];
  __shared__ int lofs[513];
  __shared__ int lcur[512];
  __shared__ int img[12288];
  const int t = threadIdx.x;
  const int base = bbase[b];
  const int bcnt = bbase[b + 1] - base;

  for (int i = t; i < 512; i += 256) { hist[i] = 0; lcur[i] = 0; }
  __syncthreads();
  for (int i = t; i < bcnt; i += 256) {
    int2 p = tmp[base + i];
    atomicAdd(&hist[p.x - c0], 1);
  }
  __syncthreads();

  int a0 = hist[2 * t], a1 = hist[2 * t + 1];
  int v = a0 + a1;
  scanbuf[t] = v;
  __syncthreads();
  for (int d = 1; d < 256; d <<= 1) {
    int u = (t >= d) ? scanbuf[t - d] : 0;
    __syncthreads();
    scanbuf[t] += u;
    __syncthreads();
  }
  int ex = scanbuf[t] - v;
  lofs[2 * t] = ex;
  lofs[2 * t + 1] = ex + a0;
  __syncthreads();

  for (int i = t; i < ncols; i += 256) {
    off[c0 + i] = base + lofs[i];
    dis[c0 + i] = rsqrtf((float)hist[i] + 1.0f);
  }
  if (b == NB - 1 && t == 0) off[n] = base + bcnt;

  if (bcnt <= 12288) {
    for (int i = t; i < bcnt; i += 256) {
      int2 p = tmp[base + i];
      int lc = p.x - c0;
      int pos = atomicAdd(&lcur[lc], 1);
      img[lofs[lc] + pos] = p.y;
    }
    __syncthreads();
    for (int i = t; i < bcnt; i += 256) csr[base + i] = img[i];
  } else {
    for (int i = t; i < bcnt; i += 256) {
      int2 p = tmp[base + i];
      int lc = p.x - c0;
      int pos = atomicAdd(&lcur[lc], 1);
      csr[base + lofs[lc] + pos] = p.y;
    }
  }
}

// ---------------- one-shot W pack (all 5 weights), fragment-ordered bf16 hi/lo ----------------
__global__ __launch_bounds__(256) void pack_all(
    const float* __restrict__ W0, const float* __restrict__ W1, const float* __restrict__ W2,
    const float* __restrict__ W3, const float* __restrict__ W4,
    u16* __restrict__ H0, u16* __restrict__ L0, u16* __restrict__ H1, u16* __restrict__ L1,
    u16* __restrict__ H2, u16* __restrict__ L2, u16* __restrict__ H3, u16* __restrict__ L3,
    u16* __restrict__ H4, u16* __restrict__ L4)
{
  int t = blockIdx.x * 256 + threadIdx.x;
  const float* W; u16* hi; u16* lo; int K, C;
  if (t < 1024)      { W = W0; hi = H0; lo = L0; K = 64;  C = 128; }
  else if (t < 3072) { W = W1; hi = H1; lo = L1; K = 128; C = 128; t -= 1024; }
  else if (t < 5120) { W = W2; hi = H2; lo = L2; K = 128; C = 128; t -= 3072; }
  else if (t < 7168) { W = W3; hi = H3; lo = L3; K = 128; C = 128; t -= 5120; }
  else               { W = W4; hi = H4; lo = L4; K = 128; C = 64;  t -= 7168; }
  const int KS = K / 32;
  int l = t & 63;
  int rest = t >> 6;
  int ks = rest % KS;
  int ct = rest / KS;
  int k0 = ks * 32 + (l >> 4) * 8;
  int c  = ct * 16 + (l & 15);
  short8 hv, lv;
  #pragma unroll
  for (int b = 0; b < 8; ++b) {
    float v = W[(size_t)(k0 + b) * C + c];
    u16 h = f2bf(v);
    hv[b] = (short)h;
    lv[b] = (short)f2bf(v - bf2f(h));
  }
  ((short8*)hi)[t] = hv;
  ((short8*)lo)[t] = lv;
}

// ---- conv GEMM: SLICED bf16 in -> SLICED bf16 out, y = (x@W)*dis; 2-term W split ----
// sliced layout: [slice][node][16 cols], slice = col/16
template<int K, int C>
__global__ __launch_bounds__(256) void gemm_conv(
    const u16* __restrict__ x,
    const u16* __restrict__ whi, const u16* __restrict__ wlo,
    const float* __restrict__ rowscale, u16* __restrict__ y, int n)
{
  constexpr int NC = C / 16;
  constexpr int KS = K / 32;
  const int t = threadIdx.x;
  const int w = t >> 6;
  const int lane = t & 63;
  const int row_base = blockIdx.x * 64 + w * 16;
  const int arow_raw = row_base + (lane & 15);
  const int arow = (arow_raw < n) ? arow_raw : 0;
  const int asub = (lane >> 4) * 8;      // 0,8,16,24
  const int s_hi = asub >> 4;            // 0 or 1
  const int s_of = asub & 15;            // 0 or 8

  f32x4 acc[NC];
  #pragma unroll
  for (int ct = 0; ct < NC; ++ct) acc[ct] = (f32x4){0.f, 0.f, 0.f, 0.f};

  const short8* WH = (const short8*)whi;
  const short8* WL = (const short8*)wlo;

  #pragma unroll
  for (int ks = 0; ks < KS; ++ks) {
    short8 ah = *(const short8*)(x + ((size_t)(ks * 2 + s_hi) * n + arow) * 16 + s_of);
    #pragma unroll
    for (int ct = 0; ct < NC; ++ct) {
      short8 bh = WH[(ct * KS + ks) * 64 + lane];
      short8 bl = WL[(ct * KS + ks) * 64 + lane];
      acc[ct] = __builtin_amdgcn_mfma_f32_16x16x32_bf16(ah, bh, acc[ct], 0, 0, 0);
      acc[ct] = __builtin_amdgcn_mfma_f32_16x16x32_bf16(ah, bl, acc[ct], 0, 0, 0);
    }
  }

  const int colb = lane & 15;
  const int rsub = (lane >> 4) * 4;
  #pragma unroll
  for (int r = 0; r < 4; ++r) {
    int row = row_base + rsub + r;
    if (row >= n) continue;
    float sc = rowscale[row];
    #pragma unroll
    for (int ct = 0; ct < NC; ++ct)
      y[((size_t)ct * n + row) * 16 + colb] = f2bf(acc[ct][r] * sc);
  }
}

// ---- fused refine: x2 = lrelu(pose@Wpos+b)@Wfc + bfc -> SLICED bf16 ----
__global__ __launch_bounds__(256) void refine_fused(
    const float* __restrict__ pose,
    const u16* __restrict__ wph, const u16* __restrict__ wpl,
    const float* __restrict__ b_pos,
    const u16* __restrict__ wfh, const u16* __restrict__ wfl,
    const float* __restrict__ b_fc,
    u16* __restrict__ y, int n)
{
  __shared__ float x1s[4][16][132];
  const int t = threadIdx.x;
  const int w = t >> 6;
  const int lane = t & 63;
  const int row_base = blockIdx.x * 64 + w * 16;
  const int colb = lane & 15;
  const int rsub = (lane >> 4) * 4;
  const int asub = (lane >> 4) * 8;

  {
    const int arow_raw = row_base + (lane & 15);
    const int arow = (arow_raw < n) ? arow_raw : 0;
    const float* xrow = pose + (size_t)arow * 64 + asub;
    f32x4 acc[8];
    #pragma unroll
    for (int ct = 0; ct < 8; ++ct) acc[ct] = (f32x4){0.f, 0.f, 0.f, 0.f};
    const short8* WH = (const short8*)wph;
    const short8* WL = (const short8*)wpl;
    #pragma unroll
    for (int ks = 0; ks < 2; ++ks) {
      float4 v0 = *(const float4*)(xrow + ks * 32);
      float4 v1 = *(const float4*)(xrow + ks * 32 + 4);
      float xv[8] = {v0.x, v0.y, v0.z, v0.w, v1.x, v1.y, v1.z, v1.w};
      short8 ah, al;
      #pragma unroll
      for (int b = 0; b < 8; ++b) {
        u16 h = f2bf(xv[b]);
        ah[b] = (short)h;
        al[b] = (short)f2bf(xv[b] - bf2f(h));
      }
      #pragma unroll
      for (int ct = 0; ct < 8; ++ct) {
        short8 bh = WH[(ct * 2 + ks) * 64 + lane];
        short8 bl = WL[(ct * 2 + ks) * 64 + lane];
        acc[ct] = __builtin_amdgcn_mfma_f32_16x16x32_bf16(ah, bh, acc[ct], 0, 0, 0);
        acc[ct] = __builtin_amdgcn_mfma_f32_16x16x32_bf16(ah, bl, acc[ct], 0, 0, 0);
        acc[ct] = __builtin_amdgcn_mfma_f32_16x16x32_bf16(al, bh, acc[ct], 0, 0, 0);
      }
    }
    #pragma unroll
    for (int ct = 0; ct < 8; ++ct) {
      float bb = b_pos[ct * 16 + colb];
      #pragma unroll
      for (int r = 0; r < 4; ++r)
        x1s[w][rsub + r][ct * 16 + colb] = lrelu(acc[ct][r] + bb);
    }
  }
  __syncthreads();

  {
    f32x4 acc[8];
    #pragma unroll
    for (int ct = 0; ct < 8; ++ct) acc[ct] = (f32x4){0.f, 0.f, 0.f, 0.f};
    const short8* WH = (const short8*)wfh;
    const short8* WL = (const short8*)wfl;
    const float* x1row = &x1s[w][lane & 15][0];
    #pragma unroll
    for (int ks = 0; ks < 4; ++ks) {
      float4 v0 = *(const float4*)(x1row + ks * 32 + asub);
      float4 v1 = *(const float4*)(x1row + ks * 32 + asub + 4);
      float xv[8] = {v0.x, v0.y, v0.z, v0.w, v1.x, v1.y, v1.z, v1.w};
      short8 ah, al;
      #pragma unroll
      for (int b = 0; b < 8; ++b) {
        u16 h = f2bf(xv[b]);
        ah[b] = (short)h;
        al[b] = (short)f2bf(xv[b] - bf2f(h));
      }
      #pragma unroll
      for (int ct = 0; ct < 8; ++ct) {
        short8 bh = WH[(ct * 4 + ks) * 64 + lane];
        short8 bl = WL[(ct * 4 + ks) * 64 + lane];
        acc[ct] = __builtin_amdgcn_mfma_f32_16x16x32_bf16(ah, bh, acc[ct], 0, 0, 0);
        acc[ct] = __builtin_amdgcn_mfma_f32_16x16x32_bf16(ah, bl, acc[ct], 0, 0, 0);
        acc[ct] = __builtin_amdgcn_mfma_f32_16x16x32_bf16(al, bh, acc[ct], 0, 0, 0);
      }
    }
    #pragma unroll
    for (int r = 0; r < 4; ++r) {
      int row = row_base + rsub + r;
      if (row >= n) continue;
      #pragma unroll
      for (int ct = 0; ct < 8; ++ct)
        y[((size_t)ct * n + row) * 16 + colb] = f2bf(acc[ct][r] + b_fc[ct * 16 + colb]);
    }
  }
}

// ---- gather (sliced, C=128): slice = blockIdx&7 -> XCD-pinned; 1 lane per node ----
__global__ __launch_bounds__(256) void gather_slice128(
    const int* __restrict__ csr, const int* __restrict__ off,
    const u16* __restrict__ hs, const float* __restrict__ dis,
    const float* __restrict__ bias, u16* __restrict__ y, int n)
{
  const int s = blockIdx.x & 7;
  const int nb = blockIdx.x >> 3;
  const int node = nb * 256 + threadIdx.x;
  if (node >= n) return;
  const int o = off[node];
  const int d = off[node + 1] - o;
  const float dd = dis[node];
  const uint4* sb = (const uint4*)hs + (size_t)s * n * 2;

  float acc[16];
  {
    uint4 h0 = sb[(size_t)node * 2];
    uint4 h1 = sb[(size_t)node * 2 + 1];
    acc[0] = bflo(h0.x); acc[1] = bfhi(h0.x); acc[2] = bflo(h0.y); acc[3] = bfhi(h0.y);
    acc[4] = bflo(h0.z); acc[5] = bfhi(h0.z); acc[6] = bflo(h0.w); acc[7] = bfhi(h0.w);
    acc[8] = bflo(h1.x); acc[9] = bfhi(h1.x); acc[10] = bflo(h1.y); acc[11] = bfhi(h1.y);
    acc[12] = bflo(h1.z); acc[13] = bfhi(h1.z); acc[14] = bflo(h1.w); acc[15] = bfhi(h1.w);
  }

  int j = 0;
  for (; j + 4 <= d; j += 4) {
    int i0 = csr[o + j], i1 = csr[o + j + 1], i2 = csr[o + j + 2], i3 = csr[o + j + 3];
    uint4 a0 = sb[(size_t)i0 * 2], a1 = sb[(size_t)i0 * 2 + 1];
    uint4 b0 = sb[(size_t)i1 * 2], b1 = sb[(size_t)i1 * 2 + 1];
    uint4 c0 = sb[(size_t)i2 * 2], c1 = sb[(size_t)i2 * 2 + 1];
    uint4 d0 = sb[(size_t)i3 * 2], d1 = sb[(size_t)i3 * 2 + 1];
    acc8(acc, a0); acc8(acc + 8, a1);
    acc8(acc, b0); acc8(acc + 8, b1);
    acc8(acc, c0); acc8(acc + 8, c1);
    acc8(acc, d0); acc8(acc + 8, d1);
  }
  for (; j < d; ++j) {
    int r = csr[o + j];
    acc8(acc, sb[(size_t)r * 2]);
    acc8(acc + 8, sb[(size_t)r * 2 + 1]);
  }

  const float* bp = bias + s * 16;
  float4 b0 = *(const float4*)bp, b1 = *(const float4*)(bp + 4);
  float4 b2 = *(const float4*)(bp + 8), b3 = *(const float4*)(bp + 12);
  float bb[16] = {b0.x, b0.y, b0.z, b0.w, b1.x, b1.y, b1.z, b1.w,
                  b2.x, b2.y, b2.z, b2.w, b3.x, b3.y, b3.z, b3.w};
  float res[16];
  #pragma unroll
  for (int k = 0; k < 16; ++k) res[k] = lrelu(acc[k] * dd + bb[k]);

  uint4 w0, w1;
  w0.x = packbf(res[0], res[1]);  w0.y = packbf(res[2], res[3]);
  w0.z = packbf(res[4], res[5]);  w0.w = packbf(res[6], res[7]);
  w1.x = packbf(res[8], res[9]);  w1.y = packbf(res[10], res[11]);
  w1.z = packbf(res[12], res[13]); w1.w = packbf(res[14], res[15]);
  uint4* yb = (uint4*)y + (size_t)s * n * 2 + (size_t)node * 2;
  yb[0] = w0;
  yb[1] = w1;
}

// ---- conv3: gather (sliced, C=64, 4 slices) + finalize + partial mean ----
__global__ __launch_bounds__(256) void gather_mean_slice(
    const int* __restrict__ csr, const int* __restrict__ off,
    const u16* __restrict__ hs, const float* __restrict__ dis,
    const float* __restrict__ bias, float* __restrict__ partial, int n)
{
  const int s = blockIdx.x & 3;
  const int nb = blockIdx.x >> 2;
  const int node = nb * 256 + threadIdx.x;
  const uint4* sb = (const uint4*)hs + (size_t)s * n * 2;

  float res[16];
  #pragma unroll
  for (int k = 0; k < 16; ++k) res[k] = 0.f;

  if (node < n) {
    const int o = off[node];
    const int d = off[node + 1] - o;
    const float dd = dis[node];
    float acc[16];
    {
      uint4 h0 = sb[(size_t)node * 2];
      uint4 h1 = sb[(size_t)node * 2 + 1];
      acc[0] = bflo(h0.x); acc[1] = bfhi(h0.x); acc[2] = bflo(h0.y); acc[3] = bfhi(h0.y);
      acc[4] = bflo(h0.z); acc[5] = bfhi(h0.z); acc[6] = bflo(h0.w); acc[7] = bfhi(h0.w);
      acc[8] = bflo(h1.x); acc[9] = bfhi(h1.x); acc[10] = bflo(h1.y); acc[11] = bfhi(h1.y);
      acc[12] = bflo(h1.z); acc[13] = bfhi(h1.z); acc[14] = bflo(h1.w); acc[15] = bfhi(h1.w);
    }
    int j = 0;
    for (; j + 4 <= d; j += 4) {
      int i0 = csr[o + j], i1 = csr[o + j + 1], i2 = csr[o + j + 2], i3 = csr[o + j + 3];
      uint4 a0 = sb[(size_t)i0 * 2], a1 = sb[(size_t)i0 * 2 + 1];
      uint4 b0 = sb[(size_t)i1 * 2], b1 = sb[(size_t)i1 * 2 + 1];
      uint4 c0 = sb[(size_t)i2 * 2], c1 = sb[(size_t)i2 * 2 + 1];
      uint4 d0 = sb[(size_t)i3 * 2], d1 = sb[(size_t)i3 * 2 + 1];
      acc8(acc, a0); acc8(acc + 8, a1);
      acc8(acc, b0); acc8(acc + 8, b1);
      acc8(acc, c0); acc8(acc + 8, c1);
      acc8(acc, d0); acc8(acc + 8, d1);
    }
    for (; j < d; ++j) {
      int r = csr[o + j];
      acc8(acc, sb[(size_t)r * 2]);
      acc8(acc + 8, sb[(size_t)r * 2 + 1]);
    }
    const float* bp = bias + s * 16;
    #pragma unroll
    for (int k = 0; k < 16; ++k) res[k] = lrelu(acc[k] * dd + bp[k]);
  }

  // wave-level reduce of 16 cols over 64 lanes
  #pragma unroll
  for (int st = 1; st < 64; st <<= 1)
    #pragma unroll
    for (int k = 0; k < 16; ++k) res[k] += __shfl_xor(res[k], st, 64);

  if ((threadIdx.x & 63) == 0) {
    float* slot = partial + (size_t)(nb & 31) * 64 + s * 16;
    #pragma unroll
    for (int k = 0; k < 16; ++k) atomicAdd(slot + k, res[k]);
  }
}

__global__ __launch_bounds__(64) void mean_finish(const float* __restrict__ partial,
                                                  float* __restrict__ out, int n) {
  const int c = threadIdx.x;
  float s = 0.f;
  #pragma unroll
  for (int k = 0; k < 32; ++k) s += partial[k * 64 + c];
  out[c] = s / (float)n;
}

extern "C" void kernel_launch(void* const* d_in, const int* in_sizes, int n_in,
                              void* d_out, int out_size, void* d_ws, size_t ws_size,
                              hipStream_t stream) {
  const float* pose = (const float*)d_in[0];
  const float* w_pos = (const float*)d_in[1];
  const float* b_pos = (const float*)d_in[2];
  const float* w_fc  = (const float*)d_in[3];
  const float* b_fc  = (const float*)d_in[4];
  const float* w_g1  = (const float*)d_in[5];
  const float* b_g1  = (const float*)d_in[6];
  const float* w_g2  = (const float*)d_in[7];
  const float* b_g2  = (const float*)d_in[8];
  const float* w_g3  = (const float*)d_in[9];
  const float* b_g3  = (const float*)d_in[10];
  const int*   edges = (const int*)d_in[11];

  const int n = in_sizes[0] / 64;   // N_NODES
  const int E = in_sizes[11] / 2;   // N_EDGES
  const int* rows = edges;
  const int* cols = edges + E;
  const int NB = (n + 511) >> 9;

  char* p = (char*)d_ws;
  auto alloc = [&](size_t bytes) { char* q = p; p += (bytes + 255) & ~(size_t)255; return q; };
  int*   off     = (int*)  alloc((size_t)(n + 1) * 4);
  int*   misc    = (int*)  alloc((256 + 256 + 2048) * 4);
  int*   btot    = misc;
  int*   gcur    = misc + 256;
  float* partial = (float*)(misc + 512);
  int*   bbase   = (int*)  alloc(257 * 4);
  float* dis     = (float*)alloc((size_t)n * 4);
  u16* wp_pos_h = (u16*)alloc(1024 * 16);
  u16* wp_pos_l = (u16*)alloc(1024 * 16);
  u16* wp_fc_h  = (u16*)alloc(2048 * 16);
  u16* wp_fc_l  = (u16*)alloc(2048 * 16);
  u16* wp_g1_h  = (u16*)alloc(2048 * 16);
  u16* wp_g1_l  = (u16*)alloc(2048 * 16);
  u16* wp_g2_h  = (u16*)alloc(2048 * 16);
  u16* wp_g2_l  = (u16*)alloc(2048 * 16);
  u16* wp_g3_h  = (u16*)alloc(1024 * 16);
  u16* wp_g3_l  = (u16*)alloc(1024 * 16);
  int*   csr     = (int*)  alloc((size_t)E * 4);
  u16*   bufA    = (u16*)  alloc((size_t)n * 128 * 2);
  u16*   bufB    = (u16*)  alloc((size_t)n * 128 * 2);
  int2*  tmp     = (int2*)bufA;   // consumed by bucket_csr before conv1 GEMM writes bufA

  const int eb4k        = (E + 4095) / 4096;
  const int gemm_blocks = (n + 63) / 64;
  const int nblk        = (n + 255) / 256;
  const int g128_blocks = nblk * 8;
  const int gm_blocks   = nblk * 4;

  // ---- weight packs (one launch) ----
  pack_all<<<32, 256, 0, stream>>>(w_pos, w_fc, w_g1, w_g2, w_g3,
      wp_pos_h, wp_pos_l, wp_fc_h, wp_fc_l, wp_g1_h, wp_g1_l,
      wp_g2_h, wp_g2_l, wp_g3_h, wp_g3_l);

  // ---- CSR build ----
  hipMemsetAsync(misc, 0, (256 + 256 + 2048) * 4, stream);
  bucket_cnt<<<eb4k, 256, 0, stream>>>(cols, btot, E, NB);
  scan_buckets<<<1, 256, 0, stream>>>(btot, bbase, NB);
  bin_pass<<<eb4k, 256, 0, stream>>>(rows, cols, bbase, gcur, tmp, E, NB);
  bucket_csr<<<NB, 256, 0, stream>>>(tmp, bbase, off, dis, csr, n, NB);

  // ---- refine (fused pair): pose -> bufB (sliced bf16) ----
  refine_fused<<<gemm_blocks, 256, 0, stream>>>(
      pose, wp_pos_h, wp_pos_l, b_pos, wp_fc_h, wp_fc_l, b_fc, bufB, n);

  // ---- conv1 ----
  gemm_conv<128, 128><<<gemm_blocks, 256, 0, stream>>>(bufB, wp_g1_h, wp_g1_l, dis, bufA, n);
  gather_slice128<<<g128_blocks, 256, 0, stream>>>(csr, off, bufA, dis, b_g1, bufB, n);

  // ---- conv2 ----
  gemm_conv<128, 128><<<gemm_blocks, 256, 0, stream>>>(bufB, wp_g2_h, wp_g2_l, dis, bufA, n);
  gather_slice128<<<g128_blocks, 256, 0, stream>>>(csr, off, bufA, dis, b_g2, bufB, n);

  // ---- conv3 + mean ----
  gemm_conv<128, 64><<<gemm_blocks, 256, 0, stream>>>(bufB, wp_g3_h, wp_g3_l, dis, bufA, n);
  gather_mean_slice<<<gm_blocks, 256, 0, stream>>>(csr, off, bufA, dis, b_g3, partial, n);
  mean_finish<<<1, 64, 0, stream>>>(partial, (float*)d_out, n);
}

// Round 12
// 274.507 us; speedup vs baseline: 1.5587x; 1.5587x over previous
//
#include <hip/hip_runtime.h>

#define SLOPE 0.01f

typedef __attribute__((ext_vector_type(8))) short short8;
typedef __attribute__((ext_vector_type(4))) float f32x4;
typedef unsigned short u16;
typedef unsigned int u32;
typedef unsigned char u8;

#define F8SCALE 16.0f
#define F8INV   0.0625f

__device__ __forceinline__ float lrelu(float v) { return v >= 0.0f ? v : SLOPE * v; }

__device__ __forceinline__ u16 f2bf(float f) {
  u32 u = __float_as_uint(f);
  return (u16)((u + 0x7FFF + ((u >> 16) & 1)) >> 16);
}
__device__ __forceinline__ float bf2f(u16 h) {
  return __uint_as_float(((u32)h) << 16);
}
__device__ __forceinline__ u8 f2f8(float v) {
  return (u8)__builtin_amdgcn_cvt_pk_fp8_f32(v, v, 0, false);
}
template<int SEL>
__device__ __forceinline__ float f82f(u32 w) {
  return __builtin_amdgcn_cvt_f32_fp8(w, SEL);
}

// ---------------- CSR: bucket totals (512 cols per bucket) ----------------
__global__ __launch_bounds__(256) void bucket_cnt(const int* __restrict__ cols,
                                                  int* __restrict__ btot, int E, int NB) {
  __shared__ int h[256];
  const int t = threadIdx.x;
  const int e0 = blockIdx.x * 4096;
  const int end = min(e0 + 4096, E);
  h[t] = 0;
  __syncthreads();
  for (int i = e0 + t; i < end; i += 256) atomicAdd(&h[cols[i] >> 9], 1);
  __syncthreads();
  if (t < NB && h[t]) atomicAdd(&btot[t], h[t]);
}

__global__ __launch_bounds__(256) void scan_buckets(const int* __restrict__ btot,
                                                    int* __restrict__ bbase, int NB) {
  __shared__ int s[256];
  const int t = threadIdx.x;
  int v = (t < NB) ? btot[t] : 0;
  s[t] = v;
  __syncthreads();
  for (int d = 1; d < 256; d <<= 1) {
    int u = (t >= d) ? s[t - d] : 0;
    __syncthreads();
    s[t] += u;
    __syncthreads();
  }
  bbase[t] = s[t] - v;
}

// ---------------- CSR fill pass A: LDS bucket-binning ----------------
__global__ __launch_bounds__(256) void bin_pass(const int* __restrict__ rows,
                                                const int* __restrict__ cols,
                                                const int* __restrict__ bbase,
                                                int* __restrict__ gcur,
                                                int2* __restrict__ tmp,
                                                int E, int NB) {
  __shared__ int hist[256];
  __shared__ int scanbuf[256];
  __shared__ int lstart[256];
  __shared__ int lcur[256];
  __shared__ int gbase[256];
  __shared__ int2 stage[4096];
  const int t = threadIdx.x;
  const int e0 = blockIdx.x * 4096;
  const int cnt = min(4096, E - e0);

  hist[t] = 0;
  __syncthreads();

  int ec[16], er[16];
  int m = 0;
  for (int i = t; i < cnt; i += 256) {
    int c = cols[e0 + i], r = rows[e0 + i];
    ec[m] = c; er[m] = r; ++m;
    atomicAdd(&hist[c >> 9], 1);
  }
  __syncthreads();

  int v = hist[t];
  scanbuf[t] = v;
  __syncthreads();
  for (int d = 1; d < 256; d <<= 1) {
    int u = (t >= d) ? scanbuf[t - d] : 0;
    __syncthreads();
    scanbuf[t] += u;
    __syncthreads();
  }
  lstart[t] = scanbuf[t] - v;
  lcur[t] = 0;
  __syncthreads();

  for (int k = 0; k < m; ++k) {
    int b = ec[k] >> 9;
    int p = lstart[b] + atomicAdd(&lcur[b], 1);
    stage[p] = make_int2(ec[k], er[k]);
  }
  __syncthreads();

  if (t < NB && hist[t] > 0) {
    gbase[t] = bbase[t] + atomicAdd(&gcur[t], hist[t]);
  }
  __syncthreads();

  for (int i = t; i < cnt; i += 256) {
    int2 pr = stage[i];
    int b = pr.x >> 9;
    tmp[gbase[b] + (i - lstart[b])] = pr;
  }
}

// ---------------- CSR pass B: per-bucket hist + scan + scatter + flush ----------------
__global__ __launch_bounds__(256) void bucket_csr(const int2* __restrict__ tmp,
                                                  const int* __restrict__ bbase,
                                                  int* __restrict__ off,
                                                  float* __restrict__ dis,
                                                  int* __restrict__ csr, int n, int NB) {
  const int b = blockIdx.x;
  const int c0 = b << 9;
  const int ncols = min(512, n - c0);
  __shared__ int hist[512];
  __shared__ int scanbuf[256];
  __shared__ int lofs[513];
  __shared__ int lcur[512];
  __shared__ int img[12288];
  const int t = threadIdx.x;
  const int base = bbase[b];
  const int bcnt = bbase[b + 1] - base;

  for (int i = t; i < 512; i += 256) { hist[i] = 0; lcur[i] = 0; }
  __syncthreads();
  for (int i = t; i < bcnt; i += 256) {
    int2 p = tmp[base + i];
    atomicAdd(&hist[p.x - c0], 1);
  }
  __syncthreads();

  int a0 = hist[2 * t], a1 = hist[2 * t + 1];
  int v = a0 + a1;
  scanbuf[t] = v;
  __syncthreads();
  for (int d = 1; d < 256; d <<= 1) {
    int u = (t >= d) ? scanbuf[t - d] : 0;
    __syncthreads();
    scanbuf[t] += u;
    __syncthreads();
  }
  int ex = scanbuf[t] - v;
  lofs[2 * t] = ex;
  lofs[2 * t + 1] = ex + a0;
  __syncthreads();

  for (int i = t; i < ncols; i += 256) {
    off[c0 + i] = base + lofs[i];
    dis[c0 + i] = rsqrtf((float)hist[i] + 1.0f);
  }
  if (b == NB - 1 && t == 0) off[n] = base + bcnt;

  if (bcnt <= 12288) {
    for (int i = t; i < bcnt; i += 256) {
      int2 p = tmp[base + i];
      int lc = p.x - c0;
      int pos = atomicAdd(&lcur[lc], 1);
      img[lofs[lc] + pos] = p.y;
    }
    __syncthreads();
    for (int i = t; i < bcnt; i += 256) csr[base + i] = img[i];
  } else {
    for (int i = t; i < bcnt; i += 256) {
      int2 p = tmp[base + i];
      int lc = p.x - c0;
      int pos = atomicAdd(&lcur[lc], 1);
      csr[base + lofs[lc] + pos] = p.y;
    }
  }
}

// ---------------- one-shot W pack (all 5 weights), fragment-ordered bf16 hi/lo ----------------
__global__ __launch_bounds__(256) void pack_all(
    const float* __restrict__ W0, const float* __restrict__ W1, const float* __restrict__ W2,
    const float* __restrict__ W3, const float* __restrict__ W4,
    u16* __restrict__ H0, u16* __restrict__ L0, u16* __restrict__ H1, u16* __restrict__ L1,
    u16* __restrict__ H2, u16* __restrict__ L2, u16* __restrict__ H3, u16* __restrict__ L3,
    u16* __restrict__ H4, u16* __restrict__ L4)
{
  int t = blockIdx.x * 256 + threadIdx.x;
  const float* W; u16* hi; u16* lo; int K, C;
  if (t < 1024)      { W = W0; hi = H0; lo = L0; K = 64;  C = 128; }
  else if (t < 3072) { W = W1; hi = H1; lo = L1; K = 128; C = 128; t -= 1024; }
  else if (t < 5120) { W = W2; hi = H2; lo = L2; K = 128; C = 128; t -= 3072; }
  else if (t < 7168) { W = W3; hi = H3; lo = L3; K = 128; C = 128; t -= 5120; }
  else               { W = W4; hi = H4; lo = L4; K = 128; C = 64;  t -= 7168; }
  const int KS = K / 32;
  int l = t & 63;
  int rest = t >> 6;
  int ks = rest % KS;
  int ct = rest / KS;
  int k0 = ks * 32 + (l >> 4) * 8;
  int c  = ct * 16 + (l & 15);
  short8 hv, lv;
  #pragma unroll
  for (int b = 0; b < 8; ++b) {
    float v = W[(size_t)(k0 + b) * C + c];
    u16 h = f2bf(v);
    hv[b] = (short)h;
    lv[b] = (short)f2bf(v - bf2f(h));
  }
  ((short8*)hi)[t] = hv;
  ((short8*)lo)[t] = lv;
}

// ---- conv GEMM: bf16 in -> fp8 out (x16 scale), y = f8((x@W)*dis*16); 2-term W split ----
template<int K, int C>
__global__ __launch_bounds__(256) void gemm_conv(
    const u16* __restrict__ x,
    const u16* __restrict__ whi, const u16* __restrict__ wlo,
    const float* __restrict__ rowscale, u8* __restrict__ y, int n)
{
  constexpr int NC = C / 16;
  constexpr int KS = K / 32;
  const int t = threadIdx.x;
  const int w = t >> 6;
  const int lane = t & 63;
  const int row_base = blockIdx.x * 64 + w * 16;
  const int arow_raw = row_base + (lane & 15);
  const int arow = (arow_raw < n) ? arow_raw : 0;
  const int asub = (lane >> 4) * 8;
  const u16* xrow = x + (size_t)arow * K + asub;

  f32x4 acc[NC];
  #pragma unroll
  for (int ct = 0; ct < NC; ++ct) acc[ct] = (f32x4){0.f, 0.f, 0.f, 0.f};

  const short8* WH = (const short8*)whi;
  const short8* WL = (const short8*)wlo;

  #pragma unroll
  for (int ks = 0; ks < KS; ++ks) {
    short8 ah = *(const short8*)(xrow + ks * 32);   // exact bf16 input: no lo term
    #pragma unroll
    for (int ct = 0; ct < NC; ++ct) {
      short8 bh = WH[(ct * KS + ks) * 64 + lane];
      short8 bl = WL[(ct * KS + ks) * 64 + lane];
      acc[ct] = __builtin_amdgcn_mfma_f32_16x16x32_bf16(ah, bh, acc[ct], 0, 0, 0);
      acc[ct] = __builtin_amdgcn_mfma_f32_16x16x32_bf16(ah, bl, acc[ct], 0, 0, 0);
    }
  }

  const int colb = lane & 15;
  const int rsub = (lane >> 4) * 4;
  #pragma unroll
  for (int r = 0; r < 4; ++r) {
    int row = row_base + rsub + r;
    if (row >= n) continue;
    float sc = rowscale[row] * F8SCALE;
    #pragma unroll
    for (int ct = 0; ct < NC; ++ct)
      y[(size_t)row * C + ct * 16 + colb] = f2f8(acc[ct][r] * sc);
  }
}

// ---- fused refine: x2 = lrelu(pose@Wpos+b)@Wfc + bfc -> bf16 ----
__global__ __launch_bounds__(256) void refine_fused(
    const float* __restrict__ pose,
    const u16* __restrict__ wph, const u16* __restrict__ wpl,
    const float* __restrict__ b_pos,
    const u16* __restrict__ wfh, const u16* __restrict__ wfl,
    const float* __restrict__ b_fc,
    u16* __restrict__ y, int n)
{
  __shared__ float x1s[4][16][132];
  const int t = threadIdx.x;
  const int w = t >> 6;
  const int lane = t & 63;
  const int row_base = blockIdx.x * 64 + w * 16;
  const int colb = lane & 15;
  const int rsub = (lane >> 4) * 4;
  const int asub = (lane >> 4) * 8;

  {
    const int arow_raw = row_base + (lane & 15);
    const int arow = (arow_raw < n) ? arow_raw : 0;
    const float* xrow = pose + (size_t)arow * 64 + asub;
    f32x4 acc[8];
    #pragma unroll
    for (int ct = 0; ct < 8; ++ct) acc[ct] = (f32x4){0.f, 0.f, 0.f, 0.f};
    const short8* WH = (const short8*)wph;
    const short8* WL = (const short8*)wpl;
    #pragma unroll
    for (int ks = 0; ks < 2; ++ks) {
      float4 v0 = *(const float4*)(xrow + ks * 32);
      float4 v1 = *(const float4*)(xrow + ks * 32 + 4);
      float xv[8] = {v0.x, v0.y, v0.z, v0.w, v1.x, v1.y, v1.z, v1.w};
      short8 ah, al;
      #pragma unroll
      for (int b = 0; b < 8; ++b) {
        u16 h = f2bf(xv[b]);
        ah[b] = (short)h;
        al[b] = (short)f2bf(xv[b] - bf2f(h));
      }
      #pragma unroll
      for (int ct = 0; ct < 8; ++ct) {
        short8 bh = WH[(ct * 2 + ks) * 64 + lane];
        short8 bl = WL[(ct * 2 + ks) * 64 + lane];
        acc[ct] = __builtin_amdgcn_mfma_f32_16x16x32_bf16(ah, bh, acc[ct], 0, 0, 0);
        acc[ct] = __builtin_amdgcn_mfma_f32_16x16x32_bf16(ah, bl, acc[ct], 0, 0, 0);
        acc[ct] = __builtin_amdgcn_mfma_f32_16x16x32_bf16(al, bh, acc[ct], 0, 0, 0);
      }
    }
    #pragma unroll
    for (int ct = 0; ct < 8; ++ct) {
      float bb = b_pos[ct * 16 + colb];
      #pragma unroll
      for (int r = 0; r < 4; ++r)
        x1s[w][rsub + r][ct * 16 + colb] = lrelu(acc[ct][r] + bb);
    }
  }
  __syncthreads();

  {
    f32x4 acc[8];
    #pragma unroll
    for (int ct = 0; ct < 8; ++ct) acc[ct] = (f32x4){0.f, 0.f, 0.f, 0.f};
    const short8* WH = (const short8*)wfh;
    const short8* WL = (const short8*)wfl;
    const float* x1row = &x1s[w][lane & 15][0];
    #pragma unroll
    for (int ks = 0; ks < 4; ++ks) {
      float4 v0 = *(const float4*)(x1row + ks * 32 + asub);
      float4 v1 = *(const float4*)(x1row + ks * 32 + asub + 4);
      float xv[8] = {v0.x, v0.y, v0.z, v0.w, v1.x, v1.y, v1.z, v1.w};
      short8 ah, al;
      #pragma unroll
      for (int b = 0; b < 8; ++b) {
        u16 h = f2bf(xv[b]);
        ah[b] = (short)h;
        al[b] = (short)f2bf(xv[b] - bf2f(h));
      }
      #pragma unroll
      for (int ct = 0; ct < 8; ++ct) {
        short8 bh = WH[(ct * 4 + ks) * 64 + lane];
        short8 bl = WL[(ct * 4 + ks) * 64 + lane];
        acc[ct] = __builtin_amdgcn_mfma_f32_16x16x32_bf16(ah, bh, acc[ct], 0, 0, 0);
        acc[ct] = __builtin_amdgcn_mfma_f32_16x16x32_bf16(ah, bl, acc[ct], 0, 0, 0);
        acc[ct] = __builtin_amdgcn_mfma_f32_16x16x32_bf16(al, bh, acc[ct], 0, 0, 0);
      }
    }
    #pragma unroll
    for (int r = 0; r < 4; ++r) {
      int row = row_base + rsub + r;
      if (row >= n) continue;
      #pragma unroll
      for (int ct = 0; ct < 8; ++ct)
        y[(size_t)row * 128 + ct * 16 + colb] = f2bf(acc[ct][r] + b_fc[ct * 16 + colb]);
    }
  }
}

// ---------------- fp8 gather bursts ----------------
__device__ __forceinline__ void accf8x4(float* acc, u32 w) {
  acc[0] += f82f<0>(w); acc[1] += f82f<1>(w);
  acc[2] += f82f<2>(w); acc[3] += f82f<3>(w);
}

template<int U>
__device__ __forceinline__ void gulpf8_128(const uint2* __restrict__ hsv, int idx, int j,
                                           int l, float* acc) {
  uint2 a[U];
  #pragma unroll
  for (int u = 0; u < U; ++u) {
    int r = __shfl(idx, j + u, 16);
    a[u] = hsv[(size_t)r * 16 + l];
  }
  #pragma unroll
  for (int u = 0; u < U; ++u) {
    accf8x4(acc, a[u].x);
    accf8x4(acc + 4, a[u].y);
  }
}

template<int U>
__device__ __forceinline__ void gulpf8_64(const u32* __restrict__ hsv, int idx, int j,
                                          int l, float* acc) {
  u32 a[U];
  #pragma unroll
  for (int u = 0; u < U; ++u) {
    int r = __shfl(idx, j + u, 16);
    a[u] = hsv[(size_t)r * 16 + l];
  }
  #pragma unroll
  for (int u = 0; u < U; ++u) accf8x4(acc, a[u]);
}

// ---- gather (C=128, fp8 hs -> bf16 out): 16 lanes/node, 8 cols/lane ----
__global__ __launch_bounds__(256) void gather_f8_128(
    const int* __restrict__ csr, const int* __restrict__ off,
    const u8* __restrict__ hs, const float* __restrict__ dis,
    const float* __restrict__ bias, u16* __restrict__ y, int n)
{
  const int t = threadIdx.x;
  const int l = t & 15;
  const int node = blockIdx.x * 16 + (t >> 4);
  if (node >= n) return;
  const int o = off[node];
  const int d = off[node + 1] - o;
  const float dd = dis[node] * F8INV;
  const uint2* hsv = (const uint2*)hs;    // row = 16 uint2 (128 fp8)

  float acc[8];
  {
    uint2 hv = hsv[(size_t)node * 16 + l];
    acc[0] = f82f<0>(hv.x); acc[1] = f82f<1>(hv.x);
    acc[2] = f82f<2>(hv.x); acc[3] = f82f<3>(hv.x);
    acc[4] = f82f<0>(hv.y); acc[5] = f82f<1>(hv.y);
    acc[6] = f82f<2>(hv.y); acc[7] = f82f<3>(hv.y);
  }

  for (int base = 0; base < d; base += 16) {
    const int batch = min(d - base, 16);
    int idx = (l < batch) ? csr[o + base + l] : 0;
    int j = 0;
    for (; j + 8 <= batch; j += 8) gulpf8_128<8>(hsv, idx, j, l, acc);
    if (j + 4 <= batch) { gulpf8_128<4>(hsv, idx, j, l, acc); j += 4; }
    for (; j < batch; ++j) gulpf8_128<1>(hsv, idx, j, l, acc);
  }

  float4 b0 = *(const float4*)(bias + l * 8);
  float4 b1 = *(const float4*)(bias + l * 8 + 4);
  float o0 = lrelu(acc[0] * dd + b0.x), o1 = lrelu(acc[1] * dd + b0.y);
  float o2 = lrelu(acc[2] * dd + b0.z), o3 = lrelu(acc[3] * dd + b0.w);
  float o4 = lrelu(acc[4] * dd + b1.x), o5 = lrelu(acc[5] * dd + b1.y);
  float o6 = lrelu(acc[6] * dd + b1.z), o7 = lrelu(acc[7] * dd + b1.w);
  uint4 wv;
  wv.x = ((u32)f2bf(o1) << 16) | f2bf(o0);
  wv.y = ((u32)f2bf(o3) << 16) | f2bf(o2);
  wv.z = ((u32)f2bf(o5) << 16) | f2bf(o4);
  wv.w = ((u32)f2bf(o7) << 16) | f2bf(o6);
  *(uint4*)(y + (size_t)node * 128 + l * 8) = wv;
}

// ---- conv3: gather (C=64 fp8) + finalize + block partial sums ----
__global__ __launch_bounds__(256) void gather_mean_part(
    const int* __restrict__ csr, const int* __restrict__ off,
    const u8* __restrict__ hs, const float* __restrict__ dis,
    const float* __restrict__ bias, float* __restrict__ partial, int n)
{
  const int t = threadIdx.x;
  const int l = t & 15;
  const int node = blockIdx.x * 16 + (t >> 4);
  float4 b4 = *(const float4*)(bias + l * 4);
  float4 val = make_float4(0.f, 0.f, 0.f, 0.f);

  if (node < n) {
    const int o = off[node];
    const int d = off[node + 1] - o;
    const float dd = dis[node] * F8INV;
    const u32* hsv = (const u32*)hs;      // row = 16 u32 (64 fp8)
    float acc[4];
    {
      u32 hv = hsv[(size_t)node * 16 + l];
      acc[0] = f82f<0>(hv); acc[1] = f82f<1>(hv);
      acc[2] = f82f<2>(hv); acc[3] = f82f<3>(hv);
    }
    for (int base = 0; base < d; base += 16) {
      const int batch = min(d - base, 16);
      int idx = (l < batch) ? csr[o + base + l] : 0;
      int j = 0;
      for (; j + 8 <= batch; j += 8) gulpf8_64<8>(hsv, idx, j, l, acc);
      if (j + 4 <= batch) { gulpf8_64<4>(hsv, idx, j, l, acc); j += 4; }
      for (; j < batch; ++j) gulpf8_64<1>(hsv, idx, j, l, acc);
    }
    val.x = lrelu(acc[0] * dd + b4.x);
    val.y = lrelu(acc[1] * dd + b4.y);
    val.z = lrelu(acc[2] * dd + b4.z);
    val.w = lrelu(acc[3] * dd + b4.w);
  }

  __shared__ float4 s[256];
  s[t] = val;
  __syncthreads();
  for (int offst = 128; offst >= 16; offst >>= 1) {
    if (t < offst) {
      s[t].x += s[t + offst].x; s[t].y += s[t + offst].y;
      s[t].z += s[t + offst].z; s[t].w += s[t + offst].w;
    }
    __syncthreads();
  }
  if (t < 16) {
    float* slot = partial + (size_t)(blockIdx.x & 31) * 64;
    atomicAdd(slot + t * 4 + 0, s[t].x);
    atomicAdd(slot + t * 4 + 1, s[t].y);
    atomicAdd(slot + t * 4 + 2, s[t].z);
    atomicAdd(slot + t * 4 + 3, s[t].w);
  }
}

__global__ __launch_bounds__(64) void mean_finish(const float* __restrict__ partial,
                                                  float* __restrict__ out, int n) {
  const int c = threadIdx.x;
  float s = 0.f;
  #pragma unroll
  for (int k = 0; k < 32; ++k) s += partial[k * 64 + c];
  out[c] = s / (float)n;
}

extern "C" void kernel_launch(void* const* d_in, const int* in_sizes, int n_in,
                              void* d_out, int out_size, void* d_ws, size_t ws_size,
                              hipStream_t stream) {
  const float* pose = (const float*)d_in[0];
  const float* w_pos = (const float*)d_in[1];
  const float* b_pos = (const float*)d_in[2];
  const float* w_fc  = (const float*)d_in[3];
  const float* b_fc  = (const float*)d_in[4];
  const float* w_g1  = (const float*)d_in[5];
  const float* b_g1  = (const float*)d_in[6];
  const float* w_g2  = (const float*)d_in[7];
  const float* b_g2  = (const float*)d_in[8];
  const float* w_g3  = (const float*)d_in[9];
  const float* b_g3  = (const float*)d_in[10];
  const int*   edges = (const int*)d_in[11];

  const int n = in_sizes[0] / 64;   // N_NODES
  const int E = in_sizes[11] / 2;   // N_EDGES
  const int* rows = edges;
  const int* cols = edges + E;
  const int NB = (n + 511) >> 9;

  char* p = (char*)d_ws;
  auto alloc = [&](size_t bytes) { char* q = p; p += (bytes + 255) & ~(size_t)255; return q; };
  int*   off     = (int*)  alloc((size_t)(n + 1) * 4);
  int*   misc    = (int*)  alloc((256 + 256 + 2048) * 4);
  int*   btot    = misc;
  int*   gcur    = misc + 256;
  float* partial = (float*)(misc + 512);
  int*   bbase   = (int*)  alloc(257 * 4);
  float* dis     = (float*)alloc((size_t)n * 4);
  u16* wp_pos_h = (u16*)alloc(1024 * 16);
  u16* wp_pos_l = (u16*)alloc(1024 * 16);
  u16* wp_fc_h  = (u16*)alloc(2048 * 16);
  u16* wp_fc_l  = (u16*)alloc(2048 * 16);
  u16* wp_g1_h  = (u16*)alloc(2048 * 16);
  u16* wp_g1_l  = (u16*)alloc(2048 * 16);
  u16* wp_g2_h  = (u16*)alloc(2048 * 16);
  u16* wp_g2_l  = (u16*)alloc(2048 * 16);
  u16* wp_g3_h  = (u16*)alloc(1024 * 16);
  u16* wp_g3_l  = (u16*)alloc(1024 * 16);
  int*   csr     = (int*)  alloc((size_t)E * 4);
  u8*    bufA    = (u8*)   alloc((size_t)E * 8);         // fp8 hs (12.8 MB) == tmp size
  u16*   bufB    = (u16*)  alloc((size_t)n * 128 * 2);   // bf16 activations
  int2*  tmp     = (int2*)bufA;   // consumed by bucket_csr before conv1 GEMM writes bufA

  const int eb4k        = (E + 4095) / 4096;
  const int gemm_blocks = (n + 63) / 64;
  const int g_blocks    = (n + 15) / 16;

  // ---- weight packs (one launch) ----
  pack_all<<<32, 256, 0, stream>>>(w_pos, w_fc, w_g1, w_g2, w_g3,
      wp_pos_h, wp_pos_l, wp_fc_h, wp_fc_l, wp_g1_h, wp_g1_l,
      wp_g2_h, wp_g2_l, wp_g3_h, wp_g3_l);

  // ---- CSR build ----
  hipMemsetAsync(misc, 0, (256 + 256 + 2048) * 4, stream);
  bucket_cnt<<<eb4k, 256, 0, stream>>>(cols, btot, E, NB);
  scan_buckets<<<1, 256, 0, stream>>>(btot, bbase, NB);
  bin_pass<<<eb4k, 256, 0, stream>>>(rows, cols, bbase, gcur, tmp, E, NB);
  bucket_csr<<<NB, 256, 0, stream>>>(tmp, bbase, off, dis, csr, n, NB);

  // ---- refine (fused pair): pose -> bufB (bf16) ----
  refine_fused<<<gemm_blocks, 256, 0, stream>>>(
      pose, wp_pos_h, wp_pos_l, b_pos, wp_fc_h, wp_fc_l, b_fc, bufB, n);

  // ---- conv1 ----
  gemm_conv<128, 128><<<gemm_blocks, 256, 0, stream>>>(bufB, wp_g1_h, wp_g1_l, dis, bufA, n);
  gather_f8_128<<<g_blocks, 256, 0, stream>>>(csr, off, bufA, dis, b_g1, bufB, n);

  // ---- conv2 ----
  gemm_conv<128, 128><<<gemm_blocks, 256, 0, stream>>>(bufB, wp_g2_h, wp_g2_l, dis, bufA, n);
  gather_f8_128<<<g_blocks, 256, 0, stream>>>(csr, off, bufA, dis, b_g2, bufB, n);

  // ---- conv3 + mean ----
  gemm_conv<128, 64><<<gemm_blocks, 256, 0, stream>>>(bufB, wp_g3_h, wp_g3_l, dis, bufA, n);
  gather_mean_part<<<g_blocks, 256, 0, stream>>>(csr, off, bufA, dis, b_g3, partial, n);
  mean_finish<<<1, 64, 0, stream>>>(partial, (float*)d_out, n);
}

// Round 14
// 249.248 us; speedup vs baseline: 1.7167x; 1.1013x over previous
//
#include <hip/hip_runtime.h>

#define SLOPE 0.01f
#define SLOT  14336

typedef __attribute__((ext_vector_type(8))) short short8;
typedef __attribute__((ext_vector_type(4))) float f32x4;
typedef __attribute__((ext_vector_type(2))) float f32x2;
typedef unsigned short u16;
typedef unsigned int u32;
typedef unsigned char u8;

#define F8SCALE 16.0f
#define F8INV   0.0625f

__device__ __forceinline__ float lrelu(float v) { return v >= 0.0f ? v : SLOPE * v; }

__device__ __forceinline__ u16 f2bf(float f) {
  u32 u = __float_as_uint(f);
  return (u16)((u + 0x7FFF + ((u >> 16) & 1)) >> 16);
}
__device__ __forceinline__ float bf2f(u16 h) {
  return __uint_as_float(((u32)h) << 16);
}
__device__ __forceinline__ u8 f2f8(float v) {
  return (u8)__builtin_amdgcn_cvt_pk_fp8_f32(v, v, 0, false);
}
__device__ __forceinline__ void accf8x4(float* acc, u32 w) {
  f32x2 lo = __builtin_amdgcn_cvt_pk_f32_fp8(w, false);
  f32x2 hi = __builtin_amdgcn_cvt_pk_f32_fp8(w, true);
  acc[0] += lo[0]; acc[1] += lo[1]; acc[2] += hi[0]; acc[3] += hi[1];
}
__device__ __forceinline__ void setf8x4(float* acc, u32 w) {
  f32x2 lo = __builtin_amdgcn_cvt_pk_f32_fp8(w, false);
  f32x2 hi = __builtin_amdgcn_cvt_pk_f32_fp8(w, true);
  acc[0] = lo[0]; acc[1] = lo[1]; acc[2] = hi[0]; acc[3] = hi[1];
}

// ---------------- CSR pass A: LDS bucket-binning, fixed slots, u32-packed ----------------
__global__ __launch_bounds__(256) void bin_pass(const int* __restrict__ rows,
                                                const int* __restrict__ cols,
                                                int* __restrict__ gcur,
                                                u32* __restrict__ tmp,
                                                int E, int NB) {
  __shared__ int hist[256];
  __shared__ int scanbuf[256];
  __shared__ int lstart[256];
  __shared__ int lcur[256];
  __shared__ int gbase[256];
  __shared__ u32 stage[4096];
  __shared__ u8  sbuck[4096];
  const int t = threadIdx.x;
  const int e0 = blockIdx.x * 4096;
  const int cnt = min(4096, E - e0);

  hist[t] = 0;
  __syncthreads();

  int ec[16], er[16];
  int m = 0;
  for (int i = t; i < cnt; i += 256) {
    int c = cols[e0 + i], r = rows[e0 + i];
    ec[m] = c; er[m] = r; ++m;
    atomicAdd(&hist[c >> 9], 1);
  }
  __syncthreads();

  int v = hist[t];
  scanbuf[t] = v;
  __syncthreads();
  for (int d = 1; d < 256; d <<= 1) {
    int u = (t >= d) ? scanbuf[t - d] : 0;
    __syncthreads();
    scanbuf[t] += u;
    __syncthreads();
  }
  lstart[t] = scanbuf[t] - v;
  lcur[t] = 0;
  __syncthreads();

  for (int k = 0; k < m; ++k) {
    int b = ec[k] >> 9;
    int p = lstart[b] + atomicAdd(&lcur[b], 1);
    stage[p] = ((u32)(ec[k] & 511) << 17) | (u32)er[k];
    sbuck[p] = (u8)b;
  }
  __syncthreads();

  if (t < NB && hist[t] > 0) {
    gbase[t] = t * SLOT + atomicAdd(&gcur[t], hist[t]);
  }
  __syncthreads();

  for (int i = t; i < cnt; i += 256) {
    int b = sbuck[i];
    tmp[gbase[b] + (i - lstart[b])] = stage[i];
  }
}

// ---------------- CSR pass B: per-bucket hist + scan + LDS scatter + flush ----------------
__global__ __launch_bounds__(256) void bucket_csr(const u32* __restrict__ tmp,
                                                  const int* __restrict__ gcur,
                                                  int* __restrict__ off,
                                                  int* __restrict__ deg,
                                                  float* __restrict__ dis,
                                                  int* __restrict__ csr, int n) {
  const int b = blockIdx.x;
  const int c0 = b << 9;
  const int ncols = min(512, n - c0);
  const int base = b * SLOT;
  const int bcnt = gcur[b];
  __shared__ int hist[512];
  __shared__ int scanbuf[256];
  __shared__ int lofs[512];
  __shared__ int lcur[512];
  __shared__ int img[12288];
  const int t = threadIdx.x;

  for (int i = t; i < 512; i += 256) { hist[i] = 0; lcur[i] = 0; }
  __syncthreads();
  for (int i = t; i < bcnt; i += 256) {
    atomicAdd(&hist[tmp[base + i] >> 17], 1);
  }
  __syncthreads();

  int a0 = hist[2 * t], a1 = hist[2 * t + 1];
  int v = a0 + a1;
  scanbuf[t] = v;
  __syncthreads();
  for (int d = 1; d < 256; d <<= 1) {
    int u = (t >= d) ? scanbuf[t - d] : 0;
    __syncthreads();
    scanbuf[t] += u;
    __syncthreads();
  }
  int ex = scanbuf[t] - v;
  lofs[2 * t] = ex;
  lofs[2 * t + 1] = ex + a0;
  __syncthreads();

  for (int i = t; i < ncols; i += 256) {
    off[c0 + i] = base + lofs[i];
    deg[c0 + i] = hist[i];
    dis[c0 + i] = rsqrtf((float)hist[i] + 1.0f);
  }

  if (bcnt <= 12288) {
    for (int i = t; i < bcnt; i += 256) {
      u32 p = tmp[base + i];
      int lc = p >> 17;
      int pos = atomicAdd(&lcur[lc], 1);
      img[lofs[lc] + pos] = (int)(p & 0x1FFFFu);
    }
    __syncthreads();
    for (int i = t; i < bcnt; i += 256) csr[base + i] = img[i];
  } else {  // statistically unreachable fallback
    for (int i = t; i < bcnt; i += 256) {
      u32 p = tmp[base + i];
      int lc = p >> 17;
      int pos = atomicAdd(&lcur[lc], 1);
      csr[base + lofs[lc] + pos] = (int)(p & 0x1FFFFu);
    }
  }
}

// ---------------- one-shot W pack (all 5 weights), fragment-ordered bf16 hi/lo ----------------
__global__ __launch_bounds__(256) void pack_all(
    const float* __restrict__ W0, const float* __restrict__ W1, const float* __restrict__ W2,
    const float* __restrict__ W3, const float* __restrict__ W4,
    u16* __restrict__ H0, u16* __restrict__ L0, u16* __restrict__ H1, u16* __restrict__ L1,
    u16* __restrict__ H2, u16* __restrict__ L2, u16* __restrict__ H3, u16* __restrict__ L3,
    u16* __restrict__ H4, u16* __restrict__ L4)
{
  int t = blockIdx.x * 256 + threadIdx.x;
  const float* W; u16* hi; u16* lo; int K, C;
  if (t < 1024)      { W = W0; hi = H0; lo = L0; K = 64;  C = 128; }
  else if (t < 3072) { W = W1; hi = H1; lo = L1; K = 128; C = 128; t -= 1024; }
  else if (t < 5120) { W = W2; hi = H2; lo = L2; K = 128; C = 128; t -= 3072; }
  else if (t < 7168) { W = W3; hi = H3; lo = L3; K = 128; C = 128; t -= 5120; }
  else               { W = W4; hi = H4; lo = L4; K = 128; C = 64;  t -= 7168; }
  const int KS = K / 32;
  int l = t & 63;
  int rest = t >> 6;
  int ks = rest % KS;
  int ct = rest / KS;
  int k0 = ks * 32 + (l >> 4) * 8;
  int c  = ct * 16 + (l & 15);
  short8 hv, lv;
  #pragma unroll
  for (int b = 0; b < 8; ++b) {
    float v = W[(size_t)(k0 + b) * C + c];
    u16 h = f2bf(v);
    hv[b] = (short)h;
    lv[b] = (short)f2bf(v - bf2f(h));
  }
  ((short8*)hi)[t] = hv;
  ((short8*)lo)[t] = lv;
}

// ---- conv GEMM: bf16 in -> fp8 out (x16 scale); 2-term W split ----
template<int K, int C>
__global__ __launch_bounds__(256) void gemm_conv(
    const u16* __restrict__ x,
    const u16* __restrict__ whi, const u16* __restrict__ wlo,
    const float* __restrict__ rowscale, u8* __restrict__ y, int n)
{
  constexpr int NC = C / 16;
  constexpr int KS = K / 32;
  const int t = threadIdx.x;
  const int w = t >> 6;
  const int lane = t & 63;
  const int row_base = blockIdx.x * 64 + w * 16;
  const int arow_raw = row_base + (lane & 15);
  const int arow = (arow_raw < n) ? arow_raw : 0;
  const int asub = (lane >> 4) * 8;
  const u16* xrow = x + (size_t)arow * K + asub;

  f32x4 acc[NC];
  #pragma unroll
  for (int ct = 0; ct < NC; ++ct) acc[ct] = (f32x4){0.f, 0.f, 0.f, 0.f};

  const short8* WH = (const short8*)whi;
  const short8* WL = (const short8*)wlo;

  #pragma unroll
  for (int ks = 0; ks < KS; ++ks) {
    short8 ah = *(const short8*)(xrow + ks * 32);
    #pragma unroll
    for (int ct = 0; ct < NC; ++ct) {
      short8 bh = WH[(ct * KS + ks) * 64 + lane];
      short8 bl = WL[(ct * KS + ks) * 64 + lane];
      acc[ct] = __builtin_amdgcn_mfma_f32_16x16x32_bf16(ah, bh, acc[ct], 0, 0, 0);
      acc[ct] = __builtin_amdgcn_mfma_f32_16x16x32_bf16(ah, bl, acc[ct], 0, 0, 0);
    }
  }

  const int colb = lane & 15;
  const int rsub = (lane >> 4) * 4;
  #pragma unroll
  for (int r = 0; r < 4; ++r) {
    int row = row_base + rsub + r;
    if (row >= n) continue;
    float sc = rowscale[row] * F8SCALE;
    #pragma unroll
    for (int ct = 0; ct < NC; ++ct)
      y[(size_t)row * C + ct * 16 + colb] = f2f8(acc[ct][r] * sc);
  }
}

// ---- fused refine: x2 = lrelu(pose@Wpos+b)@Wfc + bfc -> bf16; x1 staged as bf16 in LDS ----
__global__ __launch_bounds__(256) void refine_fused(
    const float* __restrict__ pose,
    const u16* __restrict__ wph, const u16* __restrict__ wpl,
    const float* __restrict__ b_pos,
    const u16* __restrict__ wfh, const u16* __restrict__ wfl,
    const float* __restrict__ b_fc,
    u16* __restrict__ y, int n)
{
  __shared__ __align__(16) u16 x1s[4][16][136];
  const int t = threadIdx.x;
  const int w = t >> 6;
  const int lane = t & 63;
  const int row_base = blockIdx.x * 64 + w * 16;
  const int colb = lane & 15;
  const int rsub = (lane >> 4) * 4;
  const int asub = (lane >> 4) * 8;

  {
    const int arow_raw = row_base + (lane & 15);
    const int arow = (arow_raw < n) ? arow_raw : 0;
    const float* xrow = pose + (size_t)arow * 64 + asub;
    f32x4 acc[8];
    #pragma unroll
    for (int ct = 0; ct < 8; ++ct) acc[ct] = (f32x4){0.f, 0.f, 0.f, 0.f};
    const short8* WH = (const short8*)wph;
    const short8* WL = (const short8*)wpl;
    #pragma unroll
    for (int ks = 0; ks < 2; ++ks) {
      float4 v0 = *(const float4*)(xrow + ks * 32);
      float4 v1 = *(const float4*)(xrow + ks * 32 + 4);
      float xv[8] = {v0.x, v0.y, v0.z, v0.w, v1.x, v1.y, v1.z, v1.w};
      short8 ah, al;
      #pragma unroll
      for (int b = 0; b < 8; ++b) {
        u16 h = f2bf(xv[b]);
        ah[b] = (short)h;
        al[b] = (short)f2bf(xv[b] - bf2f(h));
      }
      #pragma unroll
      for (int ct = 0; ct < 8; ++ct) {
        short8 bh = WH[(ct * 2 + ks) * 64 + lane];
        short8 bl = WL[(ct * 2 + ks) * 64 + lane];
        acc[ct] = __builtin_amdgcn_mfma_f32_16x16x32_bf16(ah, bh, acc[ct], 0, 0, 0);
        acc[ct] = __builtin_amdgcn_mfma_f32_16x16x32_bf16(ah, bl, acc[ct], 0, 0, 0);
        acc[ct] = __builtin_amdgcn_mfma_f32_16x16x32_bf16(al, bh, acc[ct], 0, 0, 0);
      }
    }
    #pragma unroll
    for (int ct = 0; ct < 8; ++ct) {
      float bb = b_pos[ct * 16 + colb];
      #pragma unroll
      for (int r = 0; r < 4; ++r)
        x1s[w][rsub + r][ct * 16 + colb] = f2bf(lrelu(acc[ct][r] + bb));
    }
  }
  __syncthreads();

  {
    f32x4 acc[8];
    #pragma unroll
    for (int ct = 0; ct < 8; ++ct) acc[ct] = (f32x4){0.f, 0.f, 0.f, 0.f};
    const short8* WH = (const short8*)wfh;
    const short8* WL = (const short8*)wfl;
    const u16* x1row = &x1s[w][lane & 15][0];
    #pragma unroll
    for (int ks = 0; ks < 4; ++ks) {
      short8 ah = *(const short8*)(x1row + ks * 32 + asub);   // exact bf16: 2-term
      #pragma unroll
      for (int ct = 0; ct < 8; ++ct) {
        short8 bh = WH[(ct * 4 + ks) * 64 + lane];
        short8 bl = WL[(ct * 4 + ks) * 64 + lane];
        acc[ct] = __builtin_amdgcn_mfma_f32_16x16x32_bf16(ah, bh, acc[ct], 0, 0, 0);
        acc[ct] = __builtin_amdgcn_mfma_f32_16x16x32_bf16(ah, bl, acc[ct], 0, 0, 0);
      }
    }
    #pragma unroll
    for (int r = 0; r < 4; ++r) {
      int row = row_base + rsub + r;
      if (row >= n) continue;
      #pragma unroll
      for (int ct = 0; ct < 8; ++ct)
        y[(size_t)row * 128 + ct * 16 + colb] = f2bf(acc[ct][r] + b_fc[ct * 16 + colb]);
    }
  }
}

// ---------------- fp8 gather bursts (paired cvt) ----------------
template<int U>
__device__ __forceinline__ void gulpf8_128(const uint2* __restrict__ hsv, int idx, int j,
                                           int l, float* acc) {
  uint2 a[U];
  #pragma unroll
  for (int u = 0; u < U; ++u) {
    int r = __shfl(idx, j + u, 16);
    a[u] = hsv[(size_t)r * 16 + l];
  }
  #pragma unroll
  for (int u = 0; u < U; ++u) {
    accf8x4(acc, a[u].x);
    accf8x4(acc + 4, a[u].y);
  }
}

template<int U>
__device__ __forceinline__ void gulpf8_64(const u32* __restrict__ hsv, int idx, int j,
                                          int l, float* acc) {
  u32 a[U];
  #pragma unroll
  for (int u = 0; u < U; ++u) {
    int r = __shfl(idx, j + u, 16);
    a[u] = hsv[(size_t)r * 16 + l];
  }
  #pragma unroll
  for (int u = 0; u < U; ++u) accf8x4(acc, a[u]);
}

// ---- gather (C=128, fp8 hs -> bf16 out): 16 lanes/node, 8 cols/lane ----
__global__ __launch_bounds__(256) void gather_f8_128(
    const int* __restrict__ csr, const int* __restrict__ off, const int* __restrict__ deg,
    const u8* __restrict__ hs, const float* __restrict__ dis,
    const float* __restrict__ bias, u16* __restrict__ y, int n)
{
  const int t = threadIdx.x;
  const int l = t & 15;
  const int node = blockIdx.x * 16 + (t >> 4);
  if (node >= n) return;
  const int o = off[node];
  const int d = deg[node];
  const float dd = dis[node] * F8INV;
  const uint2* hsv = (const uint2*)hs;

  float acc[8];
  {
    uint2 hv = hsv[(size_t)node * 16 + l];
    setf8x4(acc, hv.x);
    setf8x4(acc + 4, hv.y);
  }

  for (int base = 0; base < d; base += 16) {
    const int batch = min(d - base, 16);
    int idx = (l < batch) ? csr[o + base + l] : 0;
    int j = 0;
    for (; j + 8 <= batch; j += 8) gulpf8_128<8>(hsv, idx, j, l, acc);
    if (j + 4 <= batch) { gulpf8_128<4>(hsv, idx, j, l, acc); j += 4; }
    for (; j < batch; ++j) gulpf8_128<1>(hsv, idx, j, l, acc);
  }

  float4 b0 = *(const float4*)(bias + l * 8);
  float4 b1 = *(const float4*)(bias + l * 8 + 4);
  float o0 = lrelu(acc[0] * dd + b0.x), o1 = lrelu(acc[1] * dd + b0.y);
  float o2 = lrelu(acc[2] * dd + b0.z), o3 = lrelu(acc[3] * dd + b0.w);
  float o4 = lrelu(acc[4] * dd + b1.x), o5 = lrelu(acc[5] * dd + b1.y);
  float o6 = lrelu(acc[6] * dd + b1.z), o7 = lrelu(acc[7] * dd + b1.w);
  uint4 wv;
  wv.x = ((u32)f2bf(o1) << 16) | f2bf(o0);
  wv.y = ((u32)f2bf(o3) << 16) | f2bf(o2);
  wv.z = ((u32)f2bf(o5) << 16) | f2bf(o4);
  wv.w = ((u32)f2bf(o7) << 16) | f2bf(o6);
  *(uint4*)(y + (size_t)node * 128 + l * 8) = wv;
}

// ---- conv3: gather (C=64 fp8) + finalize + block partial sums ----
__global__ __launch_bounds__(256) void gather_mean_part(
    const int* __restrict__ csr, const int* __restrict__ off, const int* __restrict__ deg,
    const u8* __restrict__ hs, const float* __restrict__ dis,
    const float* __restrict__ bias, float* __restrict__ partial, int n)
{
  const int t = threadIdx.x;
  const int l = t & 15;
  const int node = blockIdx.x * 16 + (t >> 4);
  float4 b4 = *(const float4*)(bias + l * 4);
  float4 val = make_float4(0.f, 0.f, 0.f, 0.f);

  if (node < n) {
    const int o = off[node];
    const int d = deg[node];
    const float dd = dis[node] * F8INV;
    const u32* hsv = (const u32*)hs;
    float acc[4];
    setf8x4(acc, hsv[(size_t)node * 16 + l]);
    for (int base = 0; base < d; base += 16) {
      const int batch = min(d - base, 16);
      int idx = (l < batch) ? csr[o + base + l] : 0;
      int j = 0;
      for (; j + 8 <= batch; j += 8) gulpf8_64<8>(hsv, idx, j, l, acc);
      if (j + 4 <= batch) { gulpf8_64<4>(hsv, idx, j, l, acc); j += 4; }
      for (; j < batch; ++j) gulpf8_64<1>(hsv, idx, j, l, acc);
    }
    val.x = lrelu(acc[0] * dd + b4.x);
    val.y = lrelu(acc[1] * dd + b4.y);
    val.z = lrelu(acc[2] * dd + b4.z);
    val.w = lrelu(acc[3] * dd + b4.w);
  }

  __shared__ float4 s[256];
  s[t] = val;
  __syncthreads();
  for (int offst = 128; offst >= 16; offst >>= 1) {
    if (t < offst) {
      s[t].x += s[t + offst].x; s[t].y += s[t + offst].y;
      s[t].z += s[t + offst].z; s[t].w += s[t + offst].w;
    }
    __syncthreads();
  }
  if (t < 16) {
    float* slot = partial + (size_t)(blockIdx.x & 31) * 64;
    atomicAdd(slot + t * 4 + 0, s[t].x);
    atomicAdd(slot + t * 4 + 1, s[t].y);
    atomicAdd(slot + t * 4 + 2, s[t].z);
    atomicAdd(slot + t * 4 + 3, s[t].w);
  }
}

__global__ __launch_bounds__(64) void mean_finish(const float* __restrict__ partial,
                                                  float* __restrict__ out, int n) {
  const int c = threadIdx.x;
  float s = 0.f;
  #pragma unroll
  for (int k = 0; k < 32; ++k) s += partial[k * 64 + c];
  out[c] = s / (float)n;
}

extern "C" void kernel_launch(void* const* d_in, const int* in_sizes, int n_in,
                              void* d_out, int out_size, void* d_ws, size_t ws_size,
                              hipStream_t stream) {
  const float* pose = (const float*)d_in[0];
  const float* w_pos = (const float*)d_in[1];
  const float* b_pos = (const float*)d_in[2];
  const float* w_fc  = (const float*)d_in[3];
  const float* b_fc  = (const float*)d_in[4];
  const float* w_g1  = (const float*)d_in[5];
  const float* b_g1  = (const float*)d_in[6];
  const float* w_g2  = (const float*)d_in[7];
  const float* b_g2  = (const float*)d_in[8];
  const float* w_g3  = (const float*)d_in[9];
  const float* b_g3  = (const float*)d_in[10];
  const int*   edges = (const int*)d_in[11];

  const int n = in_sizes[0] / 64;   // N_NODES
  const int E = in_sizes[11] / 2;   // N_EDGES
  const int* rows = edges;
  const int* cols = edges + E;
  const int NB = (n + 511) >> 9;    // 196 for n=100k (<=256)

  char* p = (char*)d_ws;
  auto alloc = [&](size_t bytes) { char* q = p; p += (bytes + 255) & ~(size_t)255; return q; };
  int*   off     = (int*)  alloc((size_t)n * 4);
  int*   deg     = (int*)  alloc((size_t)n * 4);
  int*   misc    = (int*)  alloc((256 + 2048) * 4);   // gcur(256) | partial(2048)
  int*   gcur    = misc;
  float* partial = (float*)(misc + 256);
  float* dis     = (float*)alloc((size_t)n * 4);
  u16* wp_pos_h = (u16*)alloc(1024 * 16);
  u16* wp_pos_l = (u16*)alloc(1024 * 16);
  u16* wp_fc_h  = (u16*)alloc(2048 * 16);
  u16* wp_fc_l  = (u16*)alloc(2048 * 16);
  u16* wp_g1_h  = (u16*)alloc(2048 * 16);
  u16* wp_g1_l  = (u16*)alloc(2048 * 16);
  u16* wp_g2_h  = (u16*)alloc(2048 * 16);
  u16* wp_g2_l  = (u16*)alloc(2048 * 16);
  u16* wp_g3_h  = (u16*)alloc(1024 * 16);
  u16* wp_g3_l  = (u16*)alloc(1024 * 16);
  int*   csr     = (int*)  alloc((size_t)NB * SLOT * 4);   // bucket-padded
  // bufA doubles as: tmp (NB*SLOT u32 = 11.2MB) AND fp8 activations (n*128 = 12.8MB).
  // ROUND-13 BUG: was sized NB*SLOT*4 only -> gemm_conv overflowed into bufB. Take max.
  size_t bufA_sz = (size_t)NB * SLOT * 4;
  size_t act_sz  = (size_t)n * 128;
  if (act_sz > bufA_sz) bufA_sz = act_sz;
  u8*    bufA    = (u8*)   alloc(bufA_sz);
  u16*   bufB    = (u16*)  alloc((size_t)n * 128 * 2);     // bf16 activations
  u32*   tmp     = (u32*)bufA;   // consumed by bucket_csr before conv1 GEMM writes bufA

  const int eb4k        = (E + 4095) / 4096;
  const int gemm_blocks = (n + 63) / 64;
  const int g_blocks    = (n + 15) / 16;

  // ---- weight packs (one launch) ----
  pack_all<<<32, 256, 0, stream>>>(w_pos, w_fc, w_g1, w_g2, w_g3,
      wp_pos_h, wp_pos_l, wp_fc_h, wp_fc_l, wp_g1_h, wp_g1_l,
      wp_g2_h, wp_g2_l, wp_g3_h, wp_g3_l);

  // ---- CSR build (2 kernels) ----
  hipMemsetAsync(misc, 0, (256 + 2048) * 4, stream);
  bin_pass<<<eb4k, 256, 0, stream>>>(rows, cols, gcur, tmp, E, NB);
  bucket_csr<<<NB, 256, 0, stream>>>(tmp, gcur, off, deg, dis, csr, n);

  // ---- refine (fused pair): pose -> bufB (bf16) ----
  refine_fused<<<gemm_blocks, 256, 0, stream>>>(
      pose, wp_pos_h, wp_pos_l, b_pos, wp_fc_h, wp_fc_l, b_fc, bufB, n);

  // ---- conv1 ----
  gemm_conv<128, 128><<<gemm_blocks, 256, 0, stream>>>(bufB, wp_g1_h, wp_g1_l, dis, bufA, n);
  gather_f8_128<<<g_blocks, 256, 0, stream>>>(csr, off, deg, bufA, dis, b_g1, bufB, n);

  // ---- conv2 ----
  gemm_conv<128, 128><<<gemm_blocks, 256, 0, stream>>>(bufB, wp_g2_h, wp_g2_l, dis, bufA, n);
  gather_f8_128<<<g_blocks, 256, 0, stream>>>(csr, off, deg, bufA, dis, b_g2, bufB, n);

  // ---- conv3 + mean ----
  gemm_conv<128, 64><<<gemm_blocks, 256, 0, stream>>>(bufB, wp_g3_h, wp_g3_l, dis, bufA, n);
  gather_mean_part<<<g_blocks, 256, 0, stream>>>(csr, off, deg, bufA, dis, b_g3, partial, n);
  mean_finish<<<1, 64, 0, stream>>>(partial, (float*)d_out, n);
}